// Round 1
// baseline (151.323 us; speedup 1.0000x reference)
//
#include <hip/hip_runtime.h>
#include <math.h>

#define NLAT 46
#define NLON 90
#define CH   256
#define HW   (NLAT*NLON)   // 4140

__device__ __forceinline__ int lower_bound_i(const int* __restrict__ a, int n, int key){
  int lo = 0, hi = n;
  while (lo < hi){ int mid = (lo + hi) >> 1; if (a[mid] < key) lo = mid + 1; else hi = mid; }
  return lo;
}

// OutT[hw][k] = sum_c X[c*HW+hw] * W[k*CH+c] + B[k]
__global__ __launch_bounds__(256) void proj_kernel(
    const float* __restrict__ qo, const float* __restrict__ ki, const float* __restrict__ vi,
    const float* __restrict__ qw, const float* __restrict__ kw, const float* __restrict__ vw,
    const float* __restrict__ qb, const float* __restrict__ kb, const float* __restrict__ vb,
    float* __restrict__ qT, float* __restrict__ kT, float* __restrict__ vT)
{
  const float *X, *W, *B; float* O;
  if (blockIdx.z == 0)      { X = qo; W = qw; B = qb; O = qT; }
  else if (blockIdx.z == 1) { X = ki; W = kw; B = kb; O = kT; }
  else                      { X = vi; W = vw; B = vb; O = vT; }

  __shared__ float Xs[16][64];   // [c][hw]
  __shared__ float Ws[16][68];   // [c][k] (+pad)

  const int tid = threadIdx.x;
  const int tx  = tid & 15;   // k micro-tile
  const int ty  = tid >> 4;   // hw micro-tile
  const int hw0 = blockIdx.x * 64;
  const int k0  = blockIdx.y * 64;

  float acc[4][4];
  #pragma unroll
  for (int i = 0; i < 4; i++)
    #pragma unroll
    for (int j = 0; j < 4; j++) acc[i][j] = 0.f;

  for (int c0 = 0; c0 < CH; c0 += 16){
    // X tile: Xs[cc][ih] = X[(c0+cc)*HW + hw0+ih], coalesced along hw
    {
      int ih = tid & 63;
      int cb = tid >> 6;     // 0..3
      #pragma unroll
      for (int r = 0; r < 4; r++){
        int cc = cb + r*4;
        int hw = hw0 + ih;
        Xs[cc][ih] = (hw < HW) ? X[(size_t)(c0+cc)*HW + hw] : 0.f;
      }
    }
    // W tile: Ws[cc][jk] = W[(k0+jk)*CH + c0+cc]
    {
      #pragma unroll
      for (int r = 0; r < 4; r++){
        int idx = tid + r*256;
        int jk = idx >> 4;
        int cc = idx & 15;
        Ws[cc][jk] = W[(size_t)(k0+jk)*CH + c0 + cc];
      }
    }
    __syncthreads();
    #pragma unroll
    for (int cc = 0; cc < 16; cc++){
      float a[4], b[4];
      #pragma unroll
      for (int i = 0; i < 4; i++) a[i] = Xs[cc][ty*4 + i];
      #pragma unroll
      for (int j = 0; j < 4; j++) b[j] = Ws[cc][tx*4 + j];
      #pragma unroll
      for (int i = 0; i < 4; i++)
        #pragma unroll
        for (int j = 0; j < 4; j++)
          acc[i][j] += a[i] * b[j];
    }
    __syncthreads();
  }

  #pragma unroll
  for (int i = 0; i < 4; i++){
    int hw = hw0 + ty*4 + i;
    if (hw >= HW) continue;
    #pragma unroll
    for (int j = 0; j < 4; j++){
      int k = k0 + tx*4 + j;
      O[(size_t)hw*CH + k] = acc[i][j] + B[k];
    }
  }
}

// One block per (t, wo). 4 waves split the neighbor list, online softmax per
// wave, merge via LDS. Lane holds 4 channels (float4); 64-wide shuffle reduce.
__global__ __launch_bounds__(256) void attn_kernel(
    const float* __restrict__ qT, const float* __restrict__ kT, const float* __restrict__ vT,
    const float* __restrict__ quad_w, const int* __restrict__ row_ids,
    const int* __restrict__ col_idx, int nnz, float* __restrict__ out)
{
  const int blk  = blockIdx.x;          // t*NLON + wo
  const int t    = blk / NLON;
  const int wo   = blk - t*NLON;
  const int tid  = threadIdx.x;
  const int lane = tid & 63;
  const int wave = tid >> 6;

  const int start = lower_bound_i(row_ids, nnz, t);
  const int end   = lower_bound_i(row_ids, nnz, t + 1);

  const float4* qv = (const float4*)(qT + (size_t)blk * CH);
  const float4  qf = qv[lane];

  float m = -INFINITY, l = 0.f;
  float4 acc = make_float4(0.f, 0.f, 0.f, 0.f);

  for (int n = start + wave; n < end; n += 4){
    int ci = col_idx[n];
    int hi = ci / NLON;
    int wi = ci - hi*NLON + wo;
    if (wi >= NLON) wi -= NLON;
    size_t off = ((size_t)hi*NLON + wi) * CH;

    const float4* kv = (const float4*)(kT + off);
    float4 kf = kv[lane];
    float s = qf.x*kf.x + qf.y*kf.y + qf.z*kf.z + qf.w*kf.w;
    #pragma unroll
    for (int o = 32; o >= 1; o >>= 1) s += __shfl_xor(s, o, 64);

    float m_new = fmaxf(m, s);
    float e  = __expf(s - m_new) * quad_w[hi];
    float sc = __expf(m - m_new);

    const float4* vv = (const float4*)(vT + off);
    float4 vf = vv[lane];

    l = l*sc + e;
    acc.x = acc.x*sc + e*vf.x;
    acc.y = acc.y*sc + e*vf.y;
    acc.z = acc.z*sc + e*vf.z;
    acc.w = acc.w*sc + e*vf.w;
    m = m_new;
  }

  __shared__ float sm[4], sl[4];
  __shared__ float sacc[4][CH];
  if (lane == 0){ sm[wave] = m; sl[wave] = l; }
  sacc[wave][lane*4+0] = acc.x;
  sacc[wave][lane*4+1] = acc.y;
  sacc[wave][lane*4+2] = acc.z;
  sacc[wave][lane*4+3] = acc.w;
  __syncthreads();

  const float M = fmaxf(fmaxf(sm[0], sm[1]), fmaxf(sm[2], sm[3]));
  float den = 0.f, num = 0.f;
  #pragma unroll
  for (int w = 0; w < 4; w++){
    float sw = __expf(sm[w] - M);   // expf(-inf)=0 handles empty waves
    den += sw * sl[w];
    num += sw * sacc[w][tid];
  }
  // out layout (b=1, c, h, w): channel = tid
  out[(size_t)tid * HW + blk] = num / den;
}

extern "C" void kernel_launch(void* const* d_in, const int* in_sizes, int n_in,
                              void* d_out, int out_size, void* d_ws, size_t ws_size,
                              hipStream_t stream)
{
  const float* qo   = (const float*)d_in[0];
  const float* ki   = (const float*)d_in[1];
  const float* vi   = (const float*)d_in[2];
  const float* qw   = (const float*)d_in[3];
  const float* kw   = (const float*)d_in[4];
  const float* vw   = (const float*)d_in[5];
  const float* qb   = (const float*)d_in[6];
  const float* kb   = (const float*)d_in[7];
  const float* vb   = (const float*)d_in[8];
  const float* quad = (const float*)d_in[9];
  const int* row_ids = (const int*)d_in[10];
  const int* col_idx = (const int*)d_in[11];
  const int nnz = in_sizes[10];

  float* ws = (float*)d_ws;
  float* qT = ws;
  float* kT = ws + (size_t)HW*CH;
  float* vT = ws + 2*(size_t)HW*CH;

  dim3 gp((HW + 63)/64, CH/64, 3);
  proj_kernel<<<gp, 256, 0, stream>>>(qo, ki, vi, qw, kw, vw, qb, kb, vb, qT, kT, vT);
  attn_kernel<<<dim3(HW), 256, 0, stream>>>(qT, kT, vT, quad, row_ids, col_idx, nnz, (float*)d_out);
}